// Round 9
// baseline (18.287 us; speedup 1.0000x reference)
//
#include <hip/hip_runtime.h>

#define D0 128
#define D1 128
#define D2 96
#define TW 16                // owned tile width in x and y
#define EXT 20               // TW + 2*2 halo (dil needs bnd+-1, bnd needs occ+-2)
#define BND 18               // EXT - 2 (region where boundary words are valid)
#define NBX (D0 / TW)        // 8
#define NBY (D1 / TW)        // 8
#define NBLKS (NBX * NBY)    // 64 partials
#define NPKW (2 * EXT * EXT * 3)      // total packed words (both arrays) = 2400
#define NOWN (TW * TW * 3)            // owned words per block = 768

// ---------------------------------------------------------------------------
// Fused: word-per-thread pack -> boundary -> 7-point dilation (d2<=1) -> counts.
// One block per 16x16 column tile; halo recomputed, no inter-block comm.
// (Single-dispatch flag-handshake variant measured WORSE (R5): cross-XCD
//  release/acquire + threadfence cost ~5.8 us vs ~1.3 us dispatch overhead.)
// ---------------------------------------------------------------------------
__global__ __launch_bounds__(512) void fused_kernel(const float* __restrict__ net,
                                                    const int* __restrict__ tgt,
                                                    uint4* __restrict__ partials) {
    __shared__ unsigned int pk[2][EXT][EXT][3];   // packed occupancy (p,g) 9.6 KB
    __shared__ unsigned int bd[2][BND][BND][3];   // boundary words (p,g)   7.8 KB
    __shared__ unsigned long long wsum[8];

    unsigned int* pkf = &pk[0][0][0][0];          // flat view: NPKW words

    const int tid  = threadIdx.x;
    const int lane = tid & 63;
    const int wid  = tid >> 6;                    // 8 waves
    const int x0   = blockIdx.x * TW;
    const int y0   = blockIdx.y * TW;

    // ---- Phase A: one thread builds one packed word (32 z-voxels = 128 B).
    // f = gr*1200 + col*3 + wz (matches pk's flat layout). 8 independent
    // dwordx4 loads per thread (ILP), 32 compares, 1 ds_write. No shuffles.
    #pragma unroll
    for (int round = 0; round < (NPKW + 511) / 512; ++round) {
        int f = round * 512 + tid;
        if (f < NPKW) {
            int gr  = (f >= NPKW / 2) ? 1 : 0;
            int r   = f - gr * (NPKW / 2);
            int col = r / 3;
            int wz  = r - col * 3;
            int cx  = x0 - 2 + col / EXT;
            int cy  = y0 - 2 + col % EXT;
            unsigned int w = 0u;
            if (cx >= 0 && cx < D0 && cy >= 0 && cy < D1) {
                long eb = ((long)(cx * D1 + cy)) * D2 + wz * 32;
                if (gr == 0) {
                    const float4* s = (const float4*)(net + eb);
                    float4 v[8];
                    #pragma unroll
                    for (int j = 0; j < 8; ++j) v[j] = s[j];
                    #pragma unroll
                    for (int j = 0; j < 8; ++j) {
                        w |= (v[j].x > 0.0f ? 1u : 0u) << (j * 4);
                        w |= (v[j].y > 0.0f ? 2u : 0u) << (j * 4);
                        w |= (v[j].z > 0.0f ? 4u : 0u) << (j * 4);
                        w |= (v[j].w > 0.0f ? 8u : 0u) << (j * 4);
                    }
                } else {
                    const int4* s = (const int4*)(tgt + eb);
                    int4 v[8];
                    #pragma unroll
                    for (int j = 0; j < 8; ++j) v[j] = s[j];
                    #pragma unroll
                    for (int j = 0; j < 8; ++j) {
                        w |= (v[j].x ? 1u : 0u) << (j * 4);
                        w |= (v[j].y ? 2u : 0u) << (j * 4);
                        w |= (v[j].z ? 4u : 0u) << (j * 4);
                        w |= (v[j].w ? 8u : 0u) << (j * 4);
                    }
                }
            }
            pkf[f] = w;
        }
    }
    __syncthreads();

    // ---- Phase B: boundary words on the 18x18 ext-1 region (both grids).
    // boundary = fg & ~(all 6 neighbors fg); out-of-volume = background
    // (pk==0 outside the volume; z shifts inject 0 at the ends).
    for (int it = tid; it < 2 * BND * BND * 3; it += 512) {
        int gr = it / (BND * BND * 3);
        int r  = it % (BND * BND * 3);
        int bx = r / (BND * 3);
        int r2 = r % (BND * 3);
        int by = r2 / 3;
        int wz = r2 % 3;
        int ex = bx + 1, ey = by + 1;
        unsigned int w = pk[gr][ex][ey][wz];
        unsigned int bres = 0u;
        if (w) {
            unsigned int nxm = pk[gr][ex - 1][ey][wz];
            unsigned int nxp = pk[gr][ex + 1][ey][wz];
            unsigned int nym = pk[gr][ex][ey - 1][wz];
            unsigned int nyp = pk[gr][ex][ey + 1][wz];
            unsigned int lo  = (wz > 0) ? pk[gr][ex][ey][wz - 1] : 0u;
            unsigned int hi  = (wz < 2) ? pk[gr][ex][ey][wz + 1] : 0u;
            unsigned int interior = w & nxm & nxp & nym & nyp
                                  & ((w << 1) | (lo >> 31))
                                  & ((w >> 1) | (hi << 31));
            bres = w & ~interior;
        }
        bd[gr][bx][by][wz] = bres;
    }
    __syncthreads();

    // ---- Phase C: dilation + counts on the owned 16x16x3 words (2 rounds).
    unsigned long long acc = 0ull;
    for (int it = tid; it < NOWN; it += 512) {
        int ox = it / (TW * 3);
        int r  = it % (TW * 3);
        int oy = r / 3;
        int wz = r % 3;
        int bx = ox + 1, by = oy + 1;
        unsigned int Bp = bd[0][bx][by][wz];
        unsigned int Bg = bd[1][bx][by][wz];

        unsigned int gzm = (wz > 0) ? bd[1][bx][by][wz - 1] : 0u;
        unsigned int gzp = (wz < 2) ? bd[1][bx][by][wz + 1] : 0u;
        unsigned int dg = Bg | (Bg << 1) | (Bg >> 1) | (gzm >> 31) | (gzp << 31)
                        | bd[1][bx - 1][by][wz] | bd[1][bx + 1][by][wz]
                        | bd[1][bx][by - 1][wz] | bd[1][bx][by + 1][wz];

        unsigned int pzm = (wz > 0) ? bd[0][bx][by][wz - 1] : 0u;
        unsigned int pzp = (wz < 2) ? bd[0][bx][by][wz + 1] : 0u;
        unsigned int dp = Bp | (Bp << 1) | (Bp >> 1) | (pzm >> 31) | (pzp << 31)
                        | bd[0][bx - 1][by][wz] | bd[0][bx + 1][by][wz]
                        | bd[0][bx][by - 1][wz] | bd[0][bx][by + 1][wz];

        unsigned int novp = __popc(Bp & dg);
        unsigned int novg = __popc(Bg & dp);
        unsigned int nbp  = __popc(Bp);
        unsigned int nbg  = __popc(Bg);
        // fields [0:16)=ovp [16:32)=ovg [32:48)=bp [48:64)=bg;
        // block sum <= 768*32 = 24576 < 65536: no cross-field carry.
        acc += (unsigned long long)novp
             + ((unsigned long long)novg << 16)
             + ((unsigned long long)nbp  << 32)
             + ((unsigned long long)nbg  << 48);
    }
    #pragma unroll
    for (int offr = 32; offr >= 1; offr >>= 1)
        acc += __shfl_down(acc, offr, 64);
    if (lane == 0) wsum[wid] = acc;
    __syncthreads();
    if (tid == 0) {
        unsigned long long t = 0ull;
        #pragma unroll
        for (int w = 0; w < 8; ++w) t += wsum[w];
        uint4 rr;
        rr.x = (unsigned int)( t        & 0xFFFF);
        rr.y = (unsigned int)((t >> 16) & 0xFFFF);
        rr.z = (unsigned int)((t >> 32) & 0xFFFF);
        rr.w = (unsigned int)((t >> 48) & 0xFFFF);
        partials[blockIdx.y * NBX + blockIdx.x] = rr;
    }
}

// ---------------------------------------------------------------------------
// Finalize: one wave; lane L reads partials[L], 6-step shuffle reduce.
// ---------------------------------------------------------------------------
__global__ void finalize_kernel(const uint4* __restrict__ partials,
                                float* __restrict__ out) {
    int lane = threadIdx.x;   // 64 threads == NBLKS
    uint4 v = partials[lane];
    unsigned int ovp = v.x, ovg = v.y, bp = v.z, bg = v.w;
    #pragma unroll
    for (int off = 32; off >= 1; off >>= 1) {
        ovp += __shfl_down(ovp, off, 64);
        ovg += __shfl_down(ovg, off, 64);
        bp  += __shfl_down(bp,  off, 64);
        bg  += __shfl_down(bg,  off, 64);
    }
    if (lane == 0) {
        float num   = (float)(ovp + ovg);
        float denom = (float)(bp + bg);
        out[0] = denom > 0.0f ? num / denom : 0.0f;
    }
}

extern "C" void kernel_launch(void* const* d_in, const int* in_sizes, int n_in,
                              void* d_out, int out_size, void* d_ws, size_t ws_size,
                              hipStream_t stream) {
    const float* net = (const float*)d_in[0];
    const int*   tgt = (const int*)d_in[1];
    float* out = (float*)d_out;
    uint4* partials = (uint4*)d_ws;   // 64 * 16 B

    fused_kernel<<<dim3(NBX, NBY), 512, 0, stream>>>(net, tgt, partials);
    finalize_kernel<<<1, 64, 0, stream>>>(partials, out);
}

// Round 10
// 12.348 us; speedup vs baseline: 1.4810x; 1.4810x over previous
//
#include <hip/hip_runtime.h>

#define D0 128
#define D1 128
#define D2 96
#define TW 8                 // owned tile width in x and y
#define EXT 12               // TW + 2*2 halo (dil needs bnd+-1, bnd needs occ+-2)
#define BND 10               // EXT - 2 (region where boundary words are valid)
#define NBX (D0 / TW)        // 16
#define NBY (D1 / TW)        // 16
#define NBLKS (NBX * NBY)    // 256 partials (== CU count: occupancy optimum, R9 lesson)
#define NPKW (2 * EXT * EXT * 3)      // total packed words (both arrays) = 864

// ---------------------------------------------------------------------------
// Fused: word-per-thread pack -> boundary -> 7-point dilation (d2<=1) -> counts.
// One block per 8x8 column tile; halo recomputed, no inter-block comm.
// Measured-worse alternatives: single-dispatch flag handshake (R5, +5.8 us,
// cross-XCD coherence); TW=16 / 64 blocks (R9, +6.0 us, only 64/256 CUs busy
// -- working set is L3-resident so extra halo bytes are free, parallelism isn't).
// ---------------------------------------------------------------------------
__global__ __launch_bounds__(512) void fused_kernel(const float* __restrict__ net,
                                                    const int* __restrict__ tgt,
                                                    uint4* __restrict__ partials) {
    __shared__ unsigned int pk[2][EXT][EXT][3];   // packed occupancy (p,g)
    __shared__ unsigned int bd[2][BND][BND][3];   // boundary words (p,g)
    __shared__ unsigned long long wsum[8];

    unsigned int* pkf = &pk[0][0][0][0];          // flat view: NPKW words

    const int tid  = threadIdx.x;
    const int lane = tid & 63;
    const int wid  = tid >> 6;                    // 8 waves
    const int x0   = blockIdx.x * TW;
    const int y0   = blockIdx.y * TW;

    // ---- Phase A: one thread builds one packed word (32 z-voxels = 128 B).
    // f = gr*432 + col*3 + wz  (matches pk's flat layout exactly).
    // 8 independent dwordx4 loads per thread (ILP), 32 compares, 1 ds_write.
    #pragma unroll
    for (int round = 0; round < 2; ++round) {
        int f = round * 512 + tid;
        if (f < NPKW) {
            int gr  = (f >= NPKW / 2) ? 1 : 0;
            int r   = f - gr * (NPKW / 2);
            int col = r / 3;
            int wz  = r - col * 3;
            int cx  = x0 - 2 + col / EXT;
            int cy  = y0 - 2 + col % EXT;
            unsigned int w = 0u;
            if (cx >= 0 && cx < D0 && cy >= 0 && cy < D1) {
                long eb = ((long)(cx * D1 + cy)) * D2 + wz * 32;
                if (gr == 0) {
                    const float4* s = (const float4*)(net + eb);
                    float4 v[8];
                    #pragma unroll
                    for (int j = 0; j < 8; ++j) v[j] = s[j];
                    #pragma unroll
                    for (int j = 0; j < 8; ++j) {
                        w |= (v[j].x > 0.0f ? 1u : 0u) << (j * 4);
                        w |= (v[j].y > 0.0f ? 2u : 0u) << (j * 4);
                        w |= (v[j].z > 0.0f ? 4u : 0u) << (j * 4);
                        w |= (v[j].w > 0.0f ? 8u : 0u) << (j * 4);
                    }
                } else {
                    const int4* s = (const int4*)(tgt + eb);
                    int4 v[8];
                    #pragma unroll
                    for (int j = 0; j < 8; ++j) v[j] = s[j];
                    #pragma unroll
                    for (int j = 0; j < 8; ++j) {
                        w |= (v[j].x ? 1u : 0u) << (j * 4);
                        w |= (v[j].y ? 2u : 0u) << (j * 4);
                        w |= (v[j].z ? 4u : 0u) << (j * 4);
                        w |= (v[j].w ? 8u : 0u) << (j * 4);
                    }
                }
            }
            pkf[f] = w;
        }
    }
    __syncthreads();

    // ---- Phase B: boundary words on the 10x10 ext-1 region (both grids).
    // boundary = fg & ~(all 6 neighbors fg); out-of-volume = background
    // (pk==0 outside the volume; z shifts inject 0 at the ends).
    for (int it = tid; it < 2 * BND * BND * 3; it += 512) {
        int gr = it / (BND * BND * 3);
        int r  = it % (BND * BND * 3);
        int bx = r / (BND * 3);
        int r2 = r % (BND * 3);
        int by = r2 / 3;
        int wz = r2 % 3;
        int ex = bx + 1, ey = by + 1;
        unsigned int w = pk[gr][ex][ey][wz];
        unsigned int bres = 0u;
        if (w) {
            unsigned int nxm = pk[gr][ex - 1][ey][wz];
            unsigned int nxp = pk[gr][ex + 1][ey][wz];
            unsigned int nym = pk[gr][ex][ey - 1][wz];
            unsigned int nyp = pk[gr][ex][ey + 1][wz];
            unsigned int lo  = (wz > 0) ? pk[gr][ex][ey][wz - 1] : 0u;
            unsigned int hi  = (wz < 2) ? pk[gr][ex][ey][wz + 1] : 0u;
            unsigned int interior = w & nxm & nxp & nym & nyp
                                  & ((w << 1) | (lo >> 31))
                                  & ((w >> 1) | (hi << 31));
            bres = w & ~interior;
        }
        bd[gr][bx][by][wz] = bres;
    }
    __syncthreads();

    // ---- Phase C: dilation + counts on the owned 8x8x3 words.
    unsigned long long acc = 0ull;
    if (tid < TW * TW * 3) {
        int ox = tid / (TW * 3);
        int r  = tid % (TW * 3);
        int oy = r / 3;
        int wz = r % 3;
        int bx = ox + 1, by = oy + 1;
        unsigned int Bp = bd[0][bx][by][wz];
        unsigned int Bg = bd[1][bx][by][wz];

        unsigned int gzm = (wz > 0) ? bd[1][bx][by][wz - 1] : 0u;
        unsigned int gzp = (wz < 2) ? bd[1][bx][by][wz + 1] : 0u;
        unsigned int dg = Bg | (Bg << 1) | (Bg >> 1) | (gzm >> 31) | (gzp << 31)
                        | bd[1][bx - 1][by][wz] | bd[1][bx + 1][by][wz]
                        | bd[1][bx][by - 1][wz] | bd[1][bx][by + 1][wz];

        unsigned int pzm = (wz > 0) ? bd[0][bx][by][wz - 1] : 0u;
        unsigned int pzp = (wz < 2) ? bd[0][bx][by][wz + 1] : 0u;
        unsigned int dp = Bp | (Bp << 1) | (Bp >> 1) | (pzm >> 31) | (pzp << 31)
                        | bd[0][bx - 1][by][wz] | bd[0][bx + 1][by][wz]
                        | bd[0][bx][by - 1][wz] | bd[0][bx][by + 1][wz];

        unsigned int novp = __popc(Bp & dg);
        unsigned int novg = __popc(Bg & dp);
        unsigned int nbp  = __popc(Bp);
        unsigned int nbg  = __popc(Bg);
        // fields [0:16)=ovp [16:32)=ovg [32:48)=bp [48:64)=bg;
        // block sum <= 192*32 = 6144 < 65536: no cross-field carry.
        acc = (unsigned long long)novp
            + ((unsigned long long)novg << 16)
            + ((unsigned long long)nbp  << 32)
            + ((unsigned long long)nbg  << 48);
    }
    #pragma unroll
    for (int offr = 32; offr >= 1; offr >>= 1)
        acc += __shfl_down(acc, offr, 64);
    if (lane == 0) wsum[wid] = acc;
    __syncthreads();
    if (tid == 0) {
        unsigned long long t = 0ull;
        #pragma unroll
        for (int w = 0; w < 8; ++w) t += wsum[w];
        uint4 rr;
        rr.x = (unsigned int)( t        & 0xFFFF);
        rr.y = (unsigned int)((t >> 16) & 0xFFFF);
        rr.z = (unsigned int)((t >> 32) & 0xFFFF);
        rr.w = (unsigned int)((t >> 48) & 0xFFFF);
        partials[blockIdx.y * NBX + blockIdx.x] = rr;
    }
}

// ---------------------------------------------------------------------------
// Finalize: one wave; lane L sums partials[L], L+64, L+128, L+192 per field,
// then 6-step shuffle reduce per field. No LDS, no extra barriers.
// ---------------------------------------------------------------------------
__global__ void finalize_kernel(const uint4* __restrict__ partials,
                                float* __restrict__ out) {
    int lane = threadIdx.x;   // 64 threads
    unsigned int ovp = 0, ovg = 0, bp = 0, bg = 0;
    #pragma unroll
    for (int k = 0; k < NBLKS / 64; ++k) {
        uint4 v = partials[k * 64 + lane];
        ovp += v.x; ovg += v.y; bp += v.z; bg += v.w;
    }
    #pragma unroll
    for (int off = 32; off >= 1; off >>= 1) {
        ovp += __shfl_down(ovp, off, 64);
        ovg += __shfl_down(ovg, off, 64);
        bp  += __shfl_down(bp,  off, 64);
        bg  += __shfl_down(bg,  off, 64);
    }
    if (lane == 0) {
        float num   = (float)(ovp + ovg);
        float denom = (float)(bp + bg);
        out[0] = denom > 0.0f ? num / denom : 0.0f;
    }
}

extern "C" void kernel_launch(void* const* d_in, const int* in_sizes, int n_in,
                              void* d_out, int out_size, void* d_ws, size_t ws_size,
                              hipStream_t stream) {
    const float* net = (const float*)d_in[0];
    const int*   tgt = (const int*)d_in[1];
    float* out = (float*)d_out;
    uint4* partials = (uint4*)d_ws;   // 256 * 16 B

    fused_kernel<<<dim3(NBX, NBY), 512, 0, stream>>>(net, tgt, partials);
    finalize_kernel<<<1, 64, 0, stream>>>(partials, out);
}